// Round 2
// baseline (431.916 us; speedup 1.0000x reference)
//
#include <hip/hip_runtime.h>

// dv = (-v + segment_sum(w * relu(v[src]) * tp[ntype[src]], dst) + stim + Vrest) / tau
// N_NODES = 500000, N_EDGES = 16000000. edge_index flat: src=[0,E), dst=[E,2E).
//
// R1: agent-scope fp32 atomics -> memory-side RMW wall (~20G/s) -> 785us.
// R2: counting sort, direct 4B random writes -> 7x write amp -> 489us scatter.
// R4: LDS-staged bucket sort + coalesced bursts -> 241us scatter @ 19% occ.
// R5: 1024-thr scatter + prefix-derived hist -> 188us scatter.
// R7: wave-per-segment accum + dst-in-regs scatter -> 420us total.
// R8: private slices + lpref; accum merges 977 tiny segments -> 420.8us.
// R9: bucket-major global sort (atomic cursor reservation, contiguous accum
//     read). scatter 144->172 (scattered 134B runs + cursor phase), accum
//     -26us, total flat 422.7. Lesson: accum was never the second cost;
//     there is a ~250us floor beyond scatter. Scatter is latency-bound:
//     VALUBusy 15%, per-k guarded chains serialize the 16M L2 gathers.
// R10 (this): (a) full-chunk fast path in scatter -- hoist stream loads +
//     8 g-gathers into regs per half-pass before any LDS atomic/store
//     (MLP 4x); (b) pad run reservations to 4 records, copy-out composes
//     uint4 stores (4x fewer store instrs, aligned 16B). Pads are
//     value=+0.0/dst=0 records: numerically inert. Slack 2048->4096,
//     host adapts slack to workspace. Predict scatter ~135us.

#define BSHIFT 10
#define BSIZE  1024              // nodes per bucket
#define NBMAX  512               // > nb = ceil(500000/1024) = 489
#define GPB    4096              // int4 groups per scatter block = 16384 edges
#define EPB    (GPB * 4)
#define SPILL_CAP 131072

// ---------------- main path ----------------

__global__ void pre_g_kernel(const float* __restrict__ v,
                             const int* __restrict__ ntype,
                             const float* __restrict__ tp,
                             float* __restrict__ g,
                             unsigned* __restrict__ gcur,
                             int n, int nb) {
    int i = blockIdx.x * blockDim.x + threadIdx.x;
    if (i < n) {
        float x = v[i];
        x = x > 0.0f ? x : 0.0f;
        g[i] = x * tp[ntype[i]];
    }
    if (i <= nb) gcur[i] = 0u;   // gcur[0..nb-1] = bucket cursors, gcur[nb] = spill count
}

// grid = nblk, 1024 threads. Bins one 16K-edge chunk into per-bucket runs in
// LDS (dst in registers across both passes; scan via shfl), then copies each
// run (padded to 4 records) to the bucket's global region at an atomically
// reserved, 16B-aligned offset.
__global__ __launch_bounds__(1024, 8)
void scatter_kernel(const int* __restrict__ src,
                    const int* __restrict__ dst,
                    const float* __restrict__ w,
                    const float* __restrict__ g,
                    unsigned* __restrict__ bucketbuf,
                    unsigned* __restrict__ gcur,
                    uint2* __restrict__ spill,
                    int G, int n_edges, int nblk, int nb, int cap) {
    __shared__ unsigned stage[EPB];      // 64 KB
    __shared__ unsigned lstart[NBMAX];   // exclusive starts (2 KB)
    __shared__ unsigned lcur[NBMAX];     // working cursors   (2 KB)
    __shared__ unsigned gposs[NBMAX];    // global positions  (2 KB)
    __shared__ unsigned wsum[16];
    int blk = blockIdx.x, tid = threadIdx.x;
    int wid = tid >> 6, lane = tid & 63;
    bool last = (blk == nblk - 1);

    if (tid < NBMAX) lcur[tid] = 0;
    __syncthreads();

    const int4*   s4 = (const int4*)src;
    const int4*   d4 = (const int4*)dst;
    const float4* w4 = (const float4*)w;
    int gstart = blk * GPB;
    int gend = gstart + GPB; if (gend > G) gend = G;
    bool full = (gend - gstart) == GPB;

    // pass 1: load dst groups into registers + local histogram.
    // Fast path: all 4 loads issued before any LDS atomic (MLP).
    int4 dreg[4];
    if (full) {
        int i0 = gstart + tid;
        int4 a = d4[i0];
        int4 b = d4[i0 + 1024];
        int4 c = d4[i0 + 2048];
        int4 d = d4[i0 + 3072];
        dreg[0] = a; dreg[1] = b; dreg[2] = c; dreg[3] = d;
        atomicAdd(&lcur[((unsigned)a.x) >> BSHIFT], 1u);
        atomicAdd(&lcur[((unsigned)a.y) >> BSHIFT], 1u);
        atomicAdd(&lcur[((unsigned)a.z) >> BSHIFT], 1u);
        atomicAdd(&lcur[((unsigned)a.w) >> BSHIFT], 1u);
        atomicAdd(&lcur[((unsigned)b.x) >> BSHIFT], 1u);
        atomicAdd(&lcur[((unsigned)b.y) >> BSHIFT], 1u);
        atomicAdd(&lcur[((unsigned)b.z) >> BSHIFT], 1u);
        atomicAdd(&lcur[((unsigned)b.w) >> BSHIFT], 1u);
        atomicAdd(&lcur[((unsigned)c.x) >> BSHIFT], 1u);
        atomicAdd(&lcur[((unsigned)c.y) >> BSHIFT], 1u);
        atomicAdd(&lcur[((unsigned)c.z) >> BSHIFT], 1u);
        atomicAdd(&lcur[((unsigned)c.w) >> BSHIFT], 1u);
        atomicAdd(&lcur[((unsigned)d.x) >> BSHIFT], 1u);
        atomicAdd(&lcur[((unsigned)d.y) >> BSHIFT], 1u);
        atomicAdd(&lcur[((unsigned)d.z) >> BSHIFT], 1u);
        atomicAdd(&lcur[((unsigned)d.w) >> BSHIFT], 1u);
    } else {
        #pragma unroll
        for (int k = 0; k < 4; k++) {
            int i = gstart + tid + k * 1024;
            if (i < gend) {
                int4 d = d4[i];
                dreg[k] = d;
                atomicAdd(&lcur[((unsigned)d.x) >> BSHIFT], 1u);
                atomicAdd(&lcur[((unsigned)d.y) >> BSHIFT], 1u);
                atomicAdd(&lcur[((unsigned)d.z) >> BSHIFT], 1u);
                atomicAdd(&lcur[((unsigned)d.w) >> BSHIFT], 1u);
            }
        }
    }
    if (last) {
        for (int i = G * 4 + tid; i < n_edges; i += 1024)
            atomicAdd(&lcur[((unsigned)dst[i]) >> BSHIFT], 1u);
    }
    __syncthreads();

    // exclusive scan over NBMAX=512 entries (first 8 waves hold counts):
    // wave-level shfl scan + cross-wave scan of 8 partials.
    unsigned cntv = (tid < NBMAX) ? lcur[tid] : 0u;
    unsigned inc = cntv;
    #pragma unroll
    for (int o = 1; o < 64; o <<= 1) {
        unsigned t = __shfl_up(inc, o, 64);
        if (lane >= o) inc += t;
    }
    if (lane == 63) wsum[wid] = inc;
    __syncthreads();
    if (tid < 64) {
        unsigned x = (lane < 16) ? wsum[lane] : 0u;
        unsigned xi = x;
        #pragma unroll
        for (int o = 1; o < 16; o <<= 1) {
            unsigned t = __shfl_up(xi, o, 64);
            if (lane >= o) xi += t;
        }
        if (lane < 16) wsum[lane] = xi - x;   // exclusive wave offsets
    }
    __syncthreads();
    if (tid < NBMAX) {
        unsigned excl = inc - cntv + wsum[wid];
        lstart[tid] = excl;
        lcur[tid] = excl;
    }
    __syncthreads();

    // pass 2: bin packed records (value top-22 bits | 10-bit local dst).
    // Fast path: per half-pass, 2 stream loads + 8 gathers in flight before
    // any LDS atomic/store.
    if (full) {
        #pragma unroll
        for (int kk = 0; kk < 2; kk++) {
            int iA = gstart + tid + (2 * kk) * 1024;
            int iB = iA + 1024;
            int4 sA = s4[iA]; int4 sB = s4[iB];
            float4 wA = w4[iA]; float4 wB = w4[iB];
            float gA0 = g[sA.x], gA1 = g[sA.y], gA2 = g[sA.z], gA3 = g[sA.w];
            float gB0 = g[sB.x], gB1 = g[sB.y], gB2 = g[sB.z], gB3 = g[sB.w];
            int4 dA = dreg[2 * kk], dB = dreg[2 * kk + 1];
            unsigned pos;
            pos = atomicAdd(&lcur[((unsigned)dA.x) >> BSHIFT], 1u);
            stage[pos] = (__float_as_uint(wA.x * gA0) & ~(unsigned)(BSIZE - 1)) | ((unsigned)dA.x & (BSIZE - 1));
            pos = atomicAdd(&lcur[((unsigned)dA.y) >> BSHIFT], 1u);
            stage[pos] = (__float_as_uint(wA.y * gA1) & ~(unsigned)(BSIZE - 1)) | ((unsigned)dA.y & (BSIZE - 1));
            pos = atomicAdd(&lcur[((unsigned)dA.z) >> BSHIFT], 1u);
            stage[pos] = (__float_as_uint(wA.z * gA2) & ~(unsigned)(BSIZE - 1)) | ((unsigned)dA.z & (BSIZE - 1));
            pos = atomicAdd(&lcur[((unsigned)dA.w) >> BSHIFT], 1u);
            stage[pos] = (__float_as_uint(wA.w * gA3) & ~(unsigned)(BSIZE - 1)) | ((unsigned)dA.w & (BSIZE - 1));
            pos = atomicAdd(&lcur[((unsigned)dB.x) >> BSHIFT], 1u);
            stage[pos] = (__float_as_uint(wB.x * gB0) & ~(unsigned)(BSIZE - 1)) | ((unsigned)dB.x & (BSIZE - 1));
            pos = atomicAdd(&lcur[((unsigned)dB.y) >> BSHIFT], 1u);
            stage[pos] = (__float_as_uint(wB.y * gB1) & ~(unsigned)(BSIZE - 1)) | ((unsigned)dB.y & (BSIZE - 1));
            pos = atomicAdd(&lcur[((unsigned)dB.z) >> BSHIFT], 1u);
            stage[pos] = (__float_as_uint(wB.z * gB2) & ~(unsigned)(BSIZE - 1)) | ((unsigned)dB.z & (BSIZE - 1));
            pos = atomicAdd(&lcur[((unsigned)dB.w) >> BSHIFT], 1u);
            stage[pos] = (__float_as_uint(wB.w * gB3) & ~(unsigned)(BSIZE - 1)) | ((unsigned)dB.w & (BSIZE - 1));
        }
    } else {
        #pragma unroll
        for (int k = 0; k < 4; k++) {
            int i = gstart + tid + k * 1024;
            if (i < gend) {
                int4 s = s4[i]; float4 wv = w4[i]; int4 d = dreg[k];
                unsigned pos;
                pos = atomicAdd(&lcur[((unsigned)d.x) >> BSHIFT], 1u);
                stage[pos] = (__float_as_uint(wv.x * g[s.x]) & ~(unsigned)(BSIZE - 1)) | ((unsigned)d.x & (BSIZE - 1));
                pos = atomicAdd(&lcur[((unsigned)d.y) >> BSHIFT], 1u);
                stage[pos] = (__float_as_uint(wv.y * g[s.y]) & ~(unsigned)(BSIZE - 1)) | ((unsigned)d.y & (BSIZE - 1));
                pos = atomicAdd(&lcur[((unsigned)d.z) >> BSHIFT], 1u);
                stage[pos] = (__float_as_uint(wv.z * g[s.z]) & ~(unsigned)(BSIZE - 1)) | ((unsigned)d.z & (BSIZE - 1));
                pos = atomicAdd(&lcur[((unsigned)d.w) >> BSHIFT], 1u);
                stage[pos] = (__float_as_uint(wv.w * g[s.w]) & ~(unsigned)(BSIZE - 1)) | ((unsigned)d.w & (BSIZE - 1));
            }
        }
    }
    if (last) {
        for (int i = G * 4 + tid; i < n_edges; i += 1024) {
            int dd = dst[i];
            unsigned b = ((unsigned)dd) >> BSHIFT;
            unsigned pos = atomicAdd(&lcur[b], 1u);
            stage[pos] = (__float_as_uint(w[i] * g[src[i]]) & ~(unsigned)(BSIZE - 1)) |
                         ((unsigned)dd & (BSIZE - 1));
        }
    }
    __syncthreads();

    // reserve global space per bucket, padded to multiples of 4 records so
    // every accepted offset is 16B-aligned (489 wave-parallel atomics)
    if (tid < nb) {
        unsigned len = lcur[tid] - lstart[tid];
        unsigned len4 = (len + 3u) & ~3u;
        unsigned p = 0u;
        if (len) {
            p = atomicAdd(&gcur[tid], len4);
            if (p + len4 > (unsigned)cap) {          // ~sigma>6 event: spill run
                atomicSub(&gcur[tid], len4);
                unsigned sp = atomicAdd(&gcur[nb], len);
                p = 0x80000000u | sp;
            }
        }
        gposs[tid] = p;
    }
    __syncthreads();

    // copy-out: wave per run, uint4-composed 16B-aligned bursts.
    // Pad slots within the reserved len4 are zero records (+0.0 to local
    // node 0 of the bucket -- numerically inert).
    for (int b = wid; b < nb; b += 16) {
        unsigned st  = lstart[b];
        unsigned len = lcur[b] - st;
        if (!len) continue;
        unsigned p = gposs[b];
        if (p & 0x80000000u) {
            unsigned sp = p & 0x7FFFFFFFu;
            for (unsigned j = lane; j < len; j += 64) {
                if (sp + j < SPILL_CAP) {
                    unsigned u = stage[st + j];
                    spill[sp + j] = make_uint2(((unsigned)b << BSHIFT) | (u & (BSIZE - 1u)),
                                               u & ~(unsigned)(BSIZE - 1));
                }
            }
        } else {
            uint4* dp4 = (uint4*)(bucketbuf + (size_t)b * (unsigned)cap + p);
            unsigned nq = (len + 3u) >> 2;
            for (unsigned q = lane; q < nq; q += 64) {
                unsigned j = q << 2;
                uint4 u;
                u.x = stage[st + j];
                u.y = (j + 1 < len) ? stage[st + j + 1] : 0u;
                u.z = (j + 2 < len) ? stage[st + j + 2] : 0u;
                u.w = (j + 3 < len) ? stage[st + j + 3] : 0u;
                dp4[q] = u;
            }
        }
    }
}

// grid = nb, 1024 threads. One contiguous uint4-coalesced region per bucket.
__global__ __launch_bounds__(1024, 2)
void accum_kernel(const unsigned* __restrict__ bucketbuf,
                  const unsigned* __restrict__ gcur,
                  const uint2* __restrict__ spill,
                  const float* __restrict__ v,
                  const float* __restrict__ stim,
                  const float* __restrict__ vrest,
                  const float* __restrict__ tau,
                  float* __restrict__ out,
                  int n_nodes, int nb, int cap) {
    __shared__ float acc[BSIZE];
    int b = blockIdx.x, tid = threadIdx.x;
    acc[tid] = 0.0f;
    __syncthreads();

    unsigned cnt = gcur[b];
    if (cnt > (unsigned)cap) cnt = (unsigned)cap;
    const unsigned* base = bucketbuf + (size_t)b * (unsigned)cap;
    const uint4* b4 = (const uint4*)base;
    unsigned nq = cnt >> 2;
    for (unsigned i = tid; i < nq; i += 1024) {
        uint4 u = b4[i];
        atomicAdd(&acc[u.x & (BSIZE - 1u)], __uint_as_float(u.x & ~(unsigned)(BSIZE - 1)));
        atomicAdd(&acc[u.y & (BSIZE - 1u)], __uint_as_float(u.y & ~(unsigned)(BSIZE - 1)));
        atomicAdd(&acc[u.z & (BSIZE - 1u)], __uint_as_float(u.z & ~(unsigned)(BSIZE - 1)));
        atomicAdd(&acc[u.w & (BSIZE - 1u)], __uint_as_float(u.w & ~(unsigned)(BSIZE - 1)));
    }
    for (unsigned i = (nq << 2) + tid; i < cnt; i += 1024) {
        unsigned u = base[i];
        atomicAdd(&acc[u & (BSIZE - 1u)], __uint_as_float(u & ~(unsigned)(BSIZE - 1)));
    }

    unsigned sn = gcur[nb];               // spill count: 0 in practice (1 load)
    if (sn) {
        if (sn > SPILL_CAP) sn = SPILL_CAP;
        for (unsigned i = tid; i < sn; i += 1024) {
            uint2 e = spill[i];
            if ((int)(e.x >> BSHIFT) == b)
                atomicAdd(&acc[e.x & (BSIZE - 1u)], __uint_as_float(e.y));
        }
    }
    __syncthreads();

    int i0 = (b << BSHIFT) + tid;
    if (i0 < n_nodes)
        out[i0] = (-v[i0] + acc[tid] + stim[i0] + vrest[i0]) / tau[i0];
}

// ---------------- fallback (agent-scope atomics, always correct) ----------------

__global__ void node_pre_kernel(const float* __restrict__ v,
                                const int* __restrict__ ntype,
                                const float* __restrict__ tp,
                                float* __restrict__ g,
                                float* __restrict__ msg, int n) {
    int i = blockIdx.x * blockDim.x + threadIdx.x;
    if (i < n) {
        float x = v[i];
        x = x > 0.0f ? x : 0.0f;
        g[i] = x * tp[ntype[i]];
        msg[i] = 0.0f;
    }
}

__global__ void edge_scatter_kernel(const int* __restrict__ src,
                                    const int* __restrict__ dst,
                                    const float* __restrict__ w,
                                    const float* __restrict__ g,
                                    float* __restrict__ msg, int n_vec) {
    int i = blockIdx.x * blockDim.x + threadIdx.x;
    if (i < n_vec) {
        int4 s = ((const int4*)src)[i];
        int4 d = ((const int4*)dst)[i];
        float4 wv = ((const float4*)w)[i];
        atomicAdd(&msg[d.x], wv.x * g[s.x]);
        atomicAdd(&msg[d.y], wv.y * g[s.y]);
        atomicAdd(&msg[d.z], wv.z * g[s.z]);
        atomicAdd(&msg[d.w], wv.w * g[s.w]);
    }
}

__global__ void edge_scatter_tail(const int* __restrict__ src,
                                  const int* __restrict__ dst,
                                  const float* __restrict__ w,
                                  const float* __restrict__ g,
                                  float* __restrict__ msg,
                                  int start, int n_edges) {
    int i = start + blockIdx.x * blockDim.x + threadIdx.x;
    if (i < n_edges) atomicAdd(&msg[dst[i]], w[i] * g[src[i]]);
}

__global__ void node_post_kernel(const float* __restrict__ v,
                                 const float* __restrict__ msg,
                                 const float* __restrict__ stim,
                                 const float* __restrict__ vrest,
                                 const float* __restrict__ tau,
                                 float* __restrict__ out, int n) {
    int i = blockIdx.x * blockDim.x + threadIdx.x;
    if (i < n)
        out[i] = (-v[i] + msg[i] + stim[i] + vrest[i]) / tau[i];
}

// ---------------- launch ----------------

extern "C" void kernel_launch(void* const* d_in, const int* in_sizes, int n_in,
                              void* d_out, int out_size, void* d_ws, size_t ws_size,
                              hipStream_t stream) {
    const float* voltage  = (const float*)d_in[0];
    const float* stimulus = (const float*)d_in[1];
    const int*   ntype    = (const int*)d_in[2];
    const int*   edge_idx = (const int*)d_in[3];
    const float* w        = (const float*)d_in[4];
    const float* vrest    = (const float*)d_in[5];
    const float* tau      = (const float*)d_in[6];
    const float* tp       = (const float*)d_in[7];
    float* out = (float*)d_out;

    const int n_nodes = in_sizes[0];
    const int n_edges = in_sizes[4];
    const int* src = edge_idx;
    const int* dst = edge_idx + n_edges;

    const int B = 256;
    const int G = n_edges / 4;
    int nblk = (G + GPB - 1) / GPB;
    if (nblk < 1) nblk = 1;
    const int nb = (n_nodes + BSIZE - 1) / BSIZE;

    auto align256 = [](size_t x) { return (x + 255) & ~(size_t)255; };

    // per-bucket capacity: mean load + slack (padding to 4-rec runs adds
    // ~1.5 rec/run ~= 1.5K/bucket). Pick the largest slack that fits ws.
    int base_cap = (int)(((long long)n_edges * BSIZE) / (long long)(n_nodes > 0 ? n_nodes : 1));
    const int slacks[3] = {4096, 3072, 2048};
    int cap = 0;
    size_t g_off = 0, gcur_off = 0, spill_off = 0, bb_off = 0, need = (size_t)-1;
    for (int si = 0; si < 3; si++) {
        int c = (base_cap + slacks[si] + 3) & ~3;
        size_t go  = 0;
        size_t gc  = align256(go + (size_t)n_nodes * 4);
        size_t sp  = align256(gc + (size_t)(nb + 1) * 4);
        size_t bb  = align256(sp + (size_t)SPILL_CAP * 8);
        size_t nd  = align256(bb + (size_t)nb * (size_t)c * 4);
        if (nd <= ws_size) {
            cap = c; g_off = go; gcur_off = gc; spill_off = sp; bb_off = bb; need = nd;
            break;
        }
    }

    if (nb < NBMAX && cap > 0 && need <= ws_size) {
        float*    g         = (float*)((char*)d_ws + g_off);
        unsigned* gcur      = (unsigned*)((char*)d_ws + gcur_off);
        uint2*    spill     = (uint2*)((char*)d_ws + spill_off);
        unsigned* bucketbuf = (unsigned*)((char*)d_ws + bb_off);

        pre_g_kernel<<<(n_nodes + B - 1) / B, B, 0, stream>>>(
            voltage, ntype, tp, g, gcur, n_nodes, nb);
        scatter_kernel<<<nblk, 1024, 0, stream>>>(
            src, dst, w, g, bucketbuf, gcur, spill, G, n_edges, nblk, nb, cap);
        accum_kernel<<<nb, 1024, 0, stream>>>(
            bucketbuf, gcur, spill, voltage, stimulus, vrest, tau, out,
            n_nodes, nb, cap);
    } else {
        float* g   = (float*)d_ws;
        float* msg = (float*)d_ws + n_nodes;
        node_pre_kernel<<<(n_nodes + B - 1) / B, B, 0, stream>>>(
            voltage, ntype, tp, g, msg, n_nodes);
        if (G > 0)
            edge_scatter_kernel<<<(G + B - 1) / B, B, 0, stream>>>(
                src, dst, w, g, msg, G);
        if (G * 4 < n_edges) {
            int rem = n_edges - G * 4;
            edge_scatter_tail<<<(rem + B - 1) / B, B, 0, stream>>>(
                src, dst, w, g, msg, G * 4, n_edges);
        }
        node_post_kernel<<<(n_nodes + B - 1) / B, B, 0, stream>>>(
            voltage, msg, stimulus, vrest, tau, out, n_nodes);
    }
}

// Round 3
// 411.480 us; speedup vs baseline: 1.0497x; 1.0497x over previous
//
#include <hip/hip_runtime.h>

// dv = (-v + segment_sum(w * relu(v[src]) * tp[ntype[src]], dst) + stim + Vrest) / tau
// N_NODES = 500000, N_EDGES = 16000000. edge_index flat: src=[0,E), dst=[E,2E).
//
// R1: agent-scope fp32 atomics -> memory-side RMW wall (~20G/s) -> 785us.
// R2: counting sort, direct 4B random writes -> 7x write amp -> 489us scatter.
// R4: LDS-staged bucket sort + coalesced bursts -> 241us scatter @ 19% occ.
// R5: 1024-thr scatter + prefix-derived hist -> 188us scatter.
// R7: wave-per-segment accum + dst-in-regs scatter -> 420us total.
// R8: private slices + lpref; accum merges 977 tiny segments -> 420.8us.
//     scatter 144us (dense copy-out).
// R9: bucket-major global sort (atomic cursor, contiguous accum read).
//     scatter 144->172 (+28 = cursor phase + 489 scattered 134B half-idle
//     runs), accum -26us, total flat 422.7.
// R10: manual MLP hoist + uint4 copy-out: scatter 172->182. REGRESSION.
//     Lesson: compiler already pipelines the guarded per-k chains; the
//     hoist only perturbed LDS-atomic scheduling (conflicts 3.8M->4.68M,
//     VGPR 24->28). Revert pass structure.
// R11 (this): R9 pass structure + BSHIFT 10->11 (2048-node buckets).
//     nb 489->245: cursor atomics halve, runs lengthen 33.5->67 records
//     (copy-out lane util ~2x, fewer store issues), accum grid 245 ~= 1
//     block/CU with acc[2048] (half the LDS-atomic contention). 11-bit
//     dst steal compensated by round-to-nearest packing (+0x400 & ~0x7FF)
//     -- error <= R9's 10-bit truncation. Predict scatter ~150-158us.

#define BSHIFT 11
#define BSIZE  2048              // nodes per bucket
#define NBMAX  256               // > nb = ceil(500000/2048) = 245
#define GPB    4096              // int4 groups per scatter block = 16384 edges
#define EPB    (GPB * 4)
#define SPILL_CAP 131072

// pack: round-to-nearest on the stolen low bits, then steal 11 for local dst
__device__ __forceinline__ unsigned pack_rec(float x, int d) {
    return ((__float_as_uint(x) + (unsigned)(BSIZE >> 1)) & ~(unsigned)(BSIZE - 1)) |
           ((unsigned)d & (BSIZE - 1));
}

// ---------------- main path ----------------

__global__ void pre_g_kernel(const float* __restrict__ v,
                             const int* __restrict__ ntype,
                             const float* __restrict__ tp,
                             float* __restrict__ g,
                             unsigned* __restrict__ gcur,
                             int n, int nb) {
    int i = blockIdx.x * blockDim.x + threadIdx.x;
    if (i < n) {
        float x = v[i];
        x = x > 0.0f ? x : 0.0f;
        g[i] = x * tp[ntype[i]];
    }
    if (i <= nb) gcur[i] = 0u;   // gcur[0..nb-1] = bucket cursors, gcur[nb] = spill count
}

// grid = nblk, 1024 threads. Bins one 16K-edge chunk into per-bucket runs in
// LDS (dst in registers across both passes; scan via shfl), then copies each
// run (padded to 4 records) to the bucket's global region at an atomically
// reserved, 16B-aligned offset.
__global__ __launch_bounds__(1024, 8)
void scatter_kernel(const int* __restrict__ src,
                    const int* __restrict__ dst,
                    const float* __restrict__ w,
                    const float* __restrict__ g,
                    unsigned* __restrict__ bucketbuf,
                    unsigned* __restrict__ gcur,
                    uint2* __restrict__ spill,
                    int G, int n_edges, int nblk, int nb, int cap) {
    __shared__ unsigned stage[EPB];      // 64 KB
    __shared__ unsigned lstart[NBMAX];   // exclusive starts (1 KB)
    __shared__ unsigned lcur[NBMAX];     // working cursors   (1 KB)
    __shared__ unsigned gposs[NBMAX];    // global positions  (1 KB)
    __shared__ unsigned wsum[16];
    int blk = blockIdx.x, tid = threadIdx.x;
    int wid = tid >> 6, lane = tid & 63;
    bool last = (blk == nblk - 1);

    if (tid < NBMAX) lcur[tid] = 0;
    __syncthreads();

    const int4*   s4 = (const int4*)src;
    const int4*   d4 = (const int4*)dst;
    const float4* w4 = (const float4*)w;
    int gstart = blk * GPB;
    int gend = gstart + GPB; if (gend > G) gend = G;

    // pass 1: load dst groups into registers + local histogram (R9 form)
    int4 dreg[4];
    #pragma unroll
    for (int k = 0; k < 4; k++) {
        int i = gstart + tid + k * 1024;
        if (i < gend) {
            int4 d = d4[i];
            dreg[k] = d;
            atomicAdd(&lcur[((unsigned)d.x) >> BSHIFT], 1u);
            atomicAdd(&lcur[((unsigned)d.y) >> BSHIFT], 1u);
            atomicAdd(&lcur[((unsigned)d.z) >> BSHIFT], 1u);
            atomicAdd(&lcur[((unsigned)d.w) >> BSHIFT], 1u);
        }
    }
    if (last) {
        for (int i = G * 4 + tid; i < n_edges; i += 1024)
            atomicAdd(&lcur[((unsigned)dst[i]) >> BSHIFT], 1u);
    }
    __syncthreads();

    // exclusive scan over NBMAX=256 entries (first 4 waves hold counts):
    // wave-level shfl scan + cross-wave scan of wave partials.
    unsigned cntv = (tid < NBMAX) ? lcur[tid] : 0u;
    unsigned inc = cntv;
    #pragma unroll
    for (int o = 1; o < 64; o <<= 1) {
        unsigned t = __shfl_up(inc, o, 64);
        if (lane >= o) inc += t;
    }
    if (lane == 63) wsum[wid] = inc;
    __syncthreads();
    if (tid < 64) {
        unsigned x = (lane < 16) ? wsum[lane] : 0u;
        unsigned xi = x;
        #pragma unroll
        for (int o = 1; o < 16; o <<= 1) {
            unsigned t = __shfl_up(xi, o, 64);
            if (lane >= o) xi += t;
        }
        if (lane < 16) wsum[lane] = xi - x;   // exclusive wave offsets
    }
    __syncthreads();
    if (tid < NBMAX) {
        unsigned excl = inc - cntv + wsum[wid];
        lstart[tid] = excl;
        lcur[tid] = excl;
    }
    __syncthreads();

    // pass 2: bin packed records (value rounded-to-nearest on low 11 bits |
    // 11-bit local dst). R9 form: per-k guarded blocks.
    #pragma unroll
    for (int k = 0; k < 4; k++) {
        int i = gstart + tid + k * 1024;
        if (i < gend) {
            int4 s = s4[i]; float4 wv = w4[i]; int4 d = dreg[k];
            {
                unsigned b = ((unsigned)d.x) >> BSHIFT;
                unsigned pos = atomicAdd(&lcur[b], 1u);
                stage[pos] = pack_rec(wv.x * g[s.x], d.x);
            }
            {
                unsigned b = ((unsigned)d.y) >> BSHIFT;
                unsigned pos = atomicAdd(&lcur[b], 1u);
                stage[pos] = pack_rec(wv.y * g[s.y], d.y);
            }
            {
                unsigned b = ((unsigned)d.z) >> BSHIFT;
                unsigned pos = atomicAdd(&lcur[b], 1u);
                stage[pos] = pack_rec(wv.z * g[s.z], d.z);
            }
            {
                unsigned b = ((unsigned)d.w) >> BSHIFT;
                unsigned pos = atomicAdd(&lcur[b], 1u);
                stage[pos] = pack_rec(wv.w * g[s.w], d.w);
            }
        }
    }
    if (last) {
        for (int i = G * 4 + tid; i < n_edges; i += 1024) {
            int dd = dst[i];
            unsigned b = ((unsigned)dd) >> BSHIFT;
            unsigned pos = atomicAdd(&lcur[b], 1u);
            stage[pos] = pack_rec(w[i] * g[src[i]], dd);
        }
    }
    __syncthreads();

    // reserve global space per bucket, padded to multiples of 4 records so
    // every accepted offset is 16B-aligned (245 wave-parallel atomics)
    if (tid < nb) {
        unsigned len = lcur[tid] - lstart[tid];
        unsigned len4 = (len + 3u) & ~3u;
        unsigned p = 0u;
        if (len) {
            p = atomicAdd(&gcur[tid], len4);
            if (p + len4 > (unsigned)cap) {          // many-sigma event: spill run
                atomicSub(&gcur[tid], len4);
                unsigned sp = atomicAdd(&gcur[nb], len);
                p = 0x80000000u | sp;
            }
        }
        gposs[tid] = p;
    }
    __syncthreads();

    // copy-out: wave per run (~67 records), uint4-composed 16B-aligned
    // bursts. Pad slots are zero records (+0.0 to local node 0): inert.
    for (int b = wid; b < nb; b += 16) {
        unsigned st  = lstart[b];
        unsigned len = lcur[b] - st;
        if (!len) continue;
        unsigned p = gposs[b];
        if (p & 0x80000000u) {
            unsigned sp = p & 0x7FFFFFFFu;
            for (unsigned j = lane; j < len; j += 64) {
                if (sp + j < SPILL_CAP) {
                    unsigned u = stage[st + j];
                    spill[sp + j] = make_uint2(((unsigned)b << BSHIFT) | (u & (BSIZE - 1u)),
                                               u & ~(unsigned)(BSIZE - 1));
                }
            }
        } else {
            uint4* dp4 = (uint4*)(bucketbuf + (size_t)b * (unsigned)cap + p);
            unsigned nq = (len + 3u) >> 2;
            for (unsigned q = lane; q < nq; q += 64) {
                unsigned j = q << 2;
                uint4 u;
                u.x = stage[st + j];
                u.y = (j + 1 < len) ? stage[st + j + 1] : 0u;
                u.z = (j + 2 < len) ? stage[st + j + 2] : 0u;
                u.w = (j + 3 < len) ? stage[st + j + 3] : 0u;
                dp4[q] = u;
            }
        }
    }
}

// grid = nb, 1024 threads. One contiguous uint4-coalesced region per bucket;
// acc[2048] in LDS, two output nodes per thread.
__global__ __launch_bounds__(1024, 2)
void accum_kernel(const unsigned* __restrict__ bucketbuf,
                  const unsigned* __restrict__ gcur,
                  const uint2* __restrict__ spill,
                  const float* __restrict__ v,
                  const float* __restrict__ stim,
                  const float* __restrict__ vrest,
                  const float* __restrict__ tau,
                  float* __restrict__ out,
                  int n_nodes, int nb, int cap) {
    __shared__ float acc[BSIZE];
    int b = blockIdx.x, tid = threadIdx.x;
    acc[tid] = 0.0f;
    acc[tid + 1024] = 0.0f;
    __syncthreads();

    unsigned cnt = gcur[b];
    if (cnt > (unsigned)cap) cnt = (unsigned)cap;
    const unsigned* base = bucketbuf + (size_t)b * (unsigned)cap;
    const uint4* b4 = (const uint4*)base;
    unsigned nq = cnt >> 2;
    for (unsigned i = tid; i < nq; i += 1024) {
        uint4 u = b4[i];
        atomicAdd(&acc[u.x & (BSIZE - 1u)], __uint_as_float(u.x & ~(unsigned)(BSIZE - 1)));
        atomicAdd(&acc[u.y & (BSIZE - 1u)], __uint_as_float(u.y & ~(unsigned)(BSIZE - 1)));
        atomicAdd(&acc[u.z & (BSIZE - 1u)], __uint_as_float(u.z & ~(unsigned)(BSIZE - 1)));
        atomicAdd(&acc[u.w & (BSIZE - 1u)], __uint_as_float(u.w & ~(unsigned)(BSIZE - 1)));
    }
    for (unsigned i = (nq << 2) + tid; i < cnt; i += 1024) {
        unsigned u = base[i];
        atomicAdd(&acc[u & (BSIZE - 1u)], __uint_as_float(u & ~(unsigned)(BSIZE - 1)));
    }

    unsigned sn = gcur[nb];               // spill count: 0 in practice (1 load)
    if (sn) {
        if (sn > SPILL_CAP) sn = SPILL_CAP;
        for (unsigned i = tid; i < sn; i += 1024) {
            uint2 e = spill[i];
            if ((int)(e.x >> BSHIFT) == b)
                atomicAdd(&acc[e.x & (BSIZE - 1u)], __uint_as_float(e.y));
        }
    }
    __syncthreads();

    int i0 = (b << BSHIFT) + tid;
    if (i0 < n_nodes)
        out[i0] = (-v[i0] + acc[tid] + stim[i0] + vrest[i0]) / tau[i0];
    int i1 = i0 + 1024;
    if (i1 < n_nodes)
        out[i1] = (-v[i1] + acc[tid + 1024] + stim[i1] + vrest[i1]) / tau[i1];
}

// ---------------- fallback (agent-scope atomics, always correct) ----------------

__global__ void node_pre_kernel(const float* __restrict__ v,
                                const int* __restrict__ ntype,
                                const float* __restrict__ tp,
                                float* __restrict__ g,
                                float* __restrict__ msg, int n) {
    int i = blockIdx.x * blockDim.x + threadIdx.x;
    if (i < n) {
        float x = v[i];
        x = x > 0.0f ? x : 0.0f;
        g[i] = x * tp[ntype[i]];
        msg[i] = 0.0f;
    }
}

__global__ void edge_scatter_kernel(const int* __restrict__ src,
                                    const int* __restrict__ dst,
                                    const float* __restrict__ w,
                                    const float* __restrict__ g,
                                    float* __restrict__ msg, int n_vec) {
    int i = blockIdx.x * blockDim.x + threadIdx.x;
    if (i < n_vec) {
        int4 s = ((const int4*)src)[i];
        int4 d = ((const int4*)dst)[i];
        float4 wv = ((const float4*)w)[i];
        atomicAdd(&msg[d.x], wv.x * g[s.x]);
        atomicAdd(&msg[d.y], wv.y * g[s.y]);
        atomicAdd(&msg[d.z], wv.z * g[s.z]);
        atomicAdd(&msg[d.w], wv.w * g[s.w]);
    }
}

__global__ void edge_scatter_tail(const int* __restrict__ src,
                                  const int* __restrict__ dst,
                                  const float* __restrict__ w,
                                  const float* __restrict__ g,
                                  float* __restrict__ msg,
                                  int start, int n_edges) {
    int i = start + blockIdx.x * blockDim.x + threadIdx.x;
    if (i < n_edges) atomicAdd(&msg[dst[i]], w[i] * g[src[i]]);
}

__global__ void node_post_kernel(const float* __restrict__ v,
                                 const float* __restrict__ msg,
                                 const float* __restrict__ stim,
                                 const float* __restrict__ vrest,
                                 const float* __restrict__ tau,
                                 float* __restrict__ out, int n) {
    int i = blockIdx.x * blockDim.x + threadIdx.x;
    if (i < n)
        out[i] = (-v[i] + msg[i] + stim[i] + vrest[i]) / tau[i];
}

// ---------------- launch ----------------

extern "C" void kernel_launch(void* const* d_in, const int* in_sizes, int n_in,
                              void* d_out, int out_size, void* d_ws, size_t ws_size,
                              hipStream_t stream) {
    const float* voltage  = (const float*)d_in[0];
    const float* stimulus = (const float*)d_in[1];
    const int*   ntype    = (const int*)d_in[2];
    const int*   edge_idx = (const int*)d_in[3];
    const float* w        = (const float*)d_in[4];
    const float* vrest    = (const float*)d_in[5];
    const float* tau      = (const float*)d_in[6];
    const float* tp       = (const float*)d_in[7];
    float* out = (float*)d_out;

    const int n_nodes = in_sizes[0];
    const int n_edges = in_sizes[4];
    const int* src = edge_idx;
    const int* dst = edge_idx + n_edges;

    const int B = 256;
    const int G = n_edges / 4;
    int nblk = (G + GPB - 1) / GPB;
    if (nblk < 1) nblk = 1;
    const int nb = (n_nodes + BSIZE - 1) / BSIZE;

    auto align256 = [](size_t x) { return (x + 255) & ~(size_t)255; };

    // per-bucket capacity: mean load (65536) + slack. Pad-to-4 adds ~1.5
    // rec/run * nblk(977) ~= 1.5K/bucket; remaining slack covers >8 sigma
    // of binomial spread (sigma ~= 255). Pick the largest slack that fits.
    int base_cap = (int)(((long long)n_edges * BSIZE) / (long long)(n_nodes > 0 ? n_nodes : 1));
    const int slacks[3] = {4096, 3072, 2048};
    int cap = 0;
    size_t g_off = 0, gcur_off = 0, spill_off = 0, bb_off = 0, need = (size_t)-1;
    for (int si = 0; si < 3; si++) {
        int c = (base_cap + slacks[si] + 3) & ~3;
        size_t go  = 0;
        size_t gc  = align256(go + (size_t)n_nodes * 4);
        size_t sp  = align256(gc + (size_t)(nb + 1) * 4);
        size_t bb  = align256(sp + (size_t)SPILL_CAP * 8);
        size_t nd  = align256(bb + (size_t)nb * (size_t)c * 4);
        if (nd <= ws_size) {
            cap = c; g_off = go; gcur_off = gc; spill_off = sp; bb_off = bb; need = nd;
            break;
        }
    }

    if (nb < NBMAX && cap > 0 && need <= ws_size) {
        float*    g         = (float*)((char*)d_ws + g_off);
        unsigned* gcur      = (unsigned*)((char*)d_ws + gcur_off);
        uint2*    spill     = (uint2*)((char*)d_ws + spill_off);
        unsigned* bucketbuf = (unsigned*)((char*)d_ws + bb_off);

        pre_g_kernel<<<(n_nodes + B - 1) / B, B, 0, stream>>>(
            voltage, ntype, tp, g, gcur, n_nodes, nb);
        scatter_kernel<<<nblk, 1024, 0, stream>>>(
            src, dst, w, g, bucketbuf, gcur, spill, G, n_edges, nblk, nb, cap);
        accum_kernel<<<nb, 1024, 0, stream>>>(
            bucketbuf, gcur, spill, voltage, stimulus, vrest, tau, out,
            n_nodes, nb, cap);
    } else {
        float* g   = (float*)d_ws;
        float* msg = (float*)d_ws + n_nodes;
        node_pre_kernel<<<(n_nodes + B - 1) / B, B, 0, stream>>>(
            voltage, ntype, tp, g, msg, n_nodes);
        if (G > 0)
            edge_scatter_kernel<<<(G + B - 1) / B, B, 0, stream>>>(
                src, dst, w, g, msg, G);
        if (G * 4 < n_edges) {
            int rem = n_edges - G * 4;
            edge_scatter_tail<<<(rem + B - 1) / B, B, 0, stream>>>(
                src, dst, w, g, msg, G * 4, n_edges);
        }
        node_post_kernel<<<(n_nodes + B - 1) / B, B, 0, stream>>>(
            voltage, msg, stimulus, vrest, tau, out, n_nodes);
    }
}

// Round 4
// 409.577 us; speedup vs baseline: 1.0545x; 1.0046x over previous
//
#include <hip/hip_runtime.h>

// dv = (-v + segment_sum(w * relu(v[src]) * tp[ntype[src]], dst) + stim + Vrest) / tau
// N_NODES = 500000, N_EDGES = 16000000. edge_index flat: src=[0,E), dst=[E,2E).
//
// R1: agent-scope fp32 atomics -> memory-side RMW wall (~20G/s) -> 785us.
// R2: counting sort, direct 4B random writes -> 7x write amp -> 489us scatter.
// R4: LDS-staged bucket sort + coalesced bursts -> 241us scatter @ 19% occ.
// R5: 1024-thr scatter + prefix-derived hist -> 188us scatter.
// R7: wave-per-segment accum + dst-in-regs scatter -> 420us total.
// R8: private slices + lpref; accum merges 977 tiny segments. scatter 144,
//     total 420.8.
// R9: bucket-major global sort (atomic cursor, contiguous accum read).
//     scatter 172 (+28 copy-out/cursor), accum -26, total flat 422.7.
// R10: manual MLP hoist: scatter 182. REGRESSION (compiler already
//     pipelines; hoist perturbed LDS-atomic scheduling). Reverted.
// R11: BSHIFT 11 (2048-node buckets, nb=245): scatter 161, total 411.5,
//     absmax 0.125 (round-to-nearest pack). total-scatter constant ~250us
//     across R9-R11 -> accum ~30us (arith) + harness-fixed overhead.
// R12 (this): dense copy-out at full lane utilization. Scan aligns every
//     bucket's LDS region to 4 records; pad slots filled with inert
//     records (+0.0, spread local idx -- also kills accum's same-address
//     pad pileup); 1-byte q->bucket map (4.3KB LDS, 77KB total still
//     2 blocks/CU); copy-out: thread q = map read + ds_read_b128 +
//     store_dwordx4. Predict scatter ~147us, WRITE +2.9MB.

#define BSHIFT 11
#define BSIZE  2048              // nodes per bucket
#define NBMAX  256               // > nb = ceil(500000/2048) = 245; fits uint8 map
#define GPB    4096              // int4 groups per scatter block = 16384 edges
#define EPB    (GPB * 4)
#define EPBP   (EPB + 1024)      // stage + per-bucket 4-alignment padding (<=735)
#define MAPSZ  (EPBP / 4)        // uint4-granule -> bucket byte map
#define SPILL_CAP 131072

// pack: round-to-nearest on the stolen low bits, then steal 11 for local dst
__device__ __forceinline__ unsigned pack_rec(float x, int d) {
    return ((__float_as_uint(x) + (unsigned)(BSIZE >> 1)) & ~(unsigned)(BSIZE - 1)) |
           ((unsigned)d & (BSIZE - 1));
}

// ---------------- main path ----------------

__global__ void pre_g_kernel(const float* __restrict__ v,
                             const int* __restrict__ ntype,
                             const float* __restrict__ tp,
                             float* __restrict__ g,
                             unsigned* __restrict__ gcur,
                             int n, int nb) {
    int i = blockIdx.x * blockDim.x + threadIdx.x;
    if (i < n) {
        float x = v[i];
        x = x > 0.0f ? x : 0.0f;
        g[i] = x * tp[ntype[i]];
    }
    if (i <= nb) gcur[i] = 0u;   // gcur[0..nb-1] = bucket cursors, gcur[nb] = spill count
}

// grid = nblk, 1024 threads. Bins one 16K-edge chunk into 4-record-aligned
// per-bucket runs in LDS, reserves global per-bucket space via atomic
// cursor, then copies out DENSELY (thread-per-uint4, byte map for bucket
// lookup) with full lane utilization.
__global__ __launch_bounds__(1024, 8)
void scatter_kernel(const int* __restrict__ src,
                    const int* __restrict__ dst,
                    const float* __restrict__ w,
                    const float* __restrict__ g,
                    unsigned* __restrict__ bucketbuf,
                    unsigned* __restrict__ gcur,
                    uint2* __restrict__ spill,
                    int G, int n_edges, int nblk, int nb, int cap) {
    __shared__ unsigned stage[EPBP];       // 69.6 KB
    __shared__ unsigned lstart[NBMAX];     // 4-aligned exclusive starts (1 KB)
    __shared__ unsigned lcur[NBMAX];       // working cursors            (1 KB)
    __shared__ unsigned gposs[NBMAX];      // global positions           (1 KB)
    __shared__ unsigned char qmap[MAPSZ];  // uint4-granule -> bucket    (4.3 KB)
    __shared__ unsigned wsum[16];
    int blk = blockIdx.x, tid = threadIdx.x;
    int wid = tid >> 6, lane = tid & 63;
    bool last = (blk == nblk - 1);

    if (tid < NBMAX) lcur[tid] = 0;
    __syncthreads();

    const int4*   s4 = (const int4*)src;
    const int4*   d4 = (const int4*)dst;
    const float4* w4 = (const float4*)w;
    int gstart = blk * GPB;
    int gend = gstart + GPB; if (gend > G) gend = G;

    // pass 1: load dst groups into registers + local histogram (R9 form)
    int4 dreg[4];
    #pragma unroll
    for (int k = 0; k < 4; k++) {
        int i = gstart + tid + k * 1024;
        if (i < gend) {
            int4 d = d4[i];
            dreg[k] = d;
            atomicAdd(&lcur[((unsigned)d.x) >> BSHIFT], 1u);
            atomicAdd(&lcur[((unsigned)d.y) >> BSHIFT], 1u);
            atomicAdd(&lcur[((unsigned)d.z) >> BSHIFT], 1u);
            atomicAdd(&lcur[((unsigned)d.w) >> BSHIFT], 1u);
        }
    }
    if (last) {
        for (int i = G * 4 + tid; i < n_edges; i += 1024)
            atomicAdd(&lcur[((unsigned)dst[i]) >> BSHIFT], 1u);
    }
    __syncthreads();

    // exclusive scan over NBMAX=256 entries of the 4-ALIGNED counts, so
    // every bucket's stage region starts on a uint4 boundary.
    unsigned rawc = (tid < NBMAX) ? lcur[tid] : 0u;
    unsigned cntv = (rawc + 3u) & ~3u;
    unsigned inc = cntv;
    #pragma unroll
    for (int o = 1; o < 64; o <<= 1) {
        unsigned t = __shfl_up(inc, o, 64);
        if (lane >= o) inc += t;
    }
    if (lane == 63) wsum[wid] = inc;
    __syncthreads();
    if (tid < 64) {
        unsigned x = (lane < 16) ? wsum[lane] : 0u;
        unsigned xi = x;
        #pragma unroll
        for (int o = 1; o < 16; o <<= 1) {
            unsigned t = __shfl_up(xi, o, 64);
            if (lane >= o) xi += t;
        }
        if (lane < 16) wsum[lane] = xi - x;   // exclusive wave offsets
    }
    __syncthreads();
    if (tid < NBMAX) {
        unsigned excl = inc - cntv + wsum[wid];
        lstart[tid] = excl;       // 4-aligned
        lcur[tid] = excl;
    }
    __syncthreads();

    // pass 2: bin packed records (R9/R11 form: per-k guarded blocks)
    #pragma unroll
    for (int k = 0; k < 4; k++) {
        int i = gstart + tid + k * 1024;
        if (i < gend) {
            int4 s = s4[i]; float4 wv = w4[i]; int4 d = dreg[k];
            {
                unsigned b = ((unsigned)d.x) >> BSHIFT;
                unsigned pos = atomicAdd(&lcur[b], 1u);
                stage[pos] = pack_rec(wv.x * g[s.x], d.x);
            }
            {
                unsigned b = ((unsigned)d.y) >> BSHIFT;
                unsigned pos = atomicAdd(&lcur[b], 1u);
                stage[pos] = pack_rec(wv.y * g[s.y], d.y);
            }
            {
                unsigned b = ((unsigned)d.z) >> BSHIFT;
                unsigned pos = atomicAdd(&lcur[b], 1u);
                stage[pos] = pack_rec(wv.z * g[s.z], d.z);
            }
            {
                unsigned b = ((unsigned)d.w) >> BSHIFT;
                unsigned pos = atomicAdd(&lcur[b], 1u);
                stage[pos] = pack_rec(wv.w * g[s.w], d.w);
            }
        }
    }
    if (last) {
        for (int i = G * 4 + tid; i < n_edges; i += 1024) {
            int dd = dst[i];
            unsigned b = ((unsigned)dd) >> BSHIFT;
            unsigned pos = atomicAdd(&lcur[b], 1u);
            stage[pos] = pack_rec(w[i] * g[src[i]], dd);
        }
    }
    __syncthreads();

    // reserve + pad + map phase (one thread per bucket):
    //  - reserve len4 records in the bucket's global region (cursor atomic)
    //  - fill LDS pad slots [end, end4) with inert records (+0.0, spread idx)
    //  - write the q->bucket byte map for this bucket's uint4 range
    if (tid < nb) {
        unsigned st   = lstart[tid];
        unsigned end  = lcur[tid];
        unsigned len  = end - st;
        unsigned len4 = (len + 3u) & ~3u;
        unsigned p = 0u;
        if (len) {
            p = atomicAdd(&gcur[tid], len4);
            if (p + len4 > (unsigned)cap) {          // many-sigma event: spill run
                atomicSub(&gcur[tid], len4);
                unsigned sp = atomicAdd(&gcur[nb], len4);
                p = 0x80000000u | sp;
            }
            for (unsigned j = end; j < st + len4; j++)
                stage[j] = j & (unsigned)(BSIZE - 1);   // value +0.0, spread idx
            for (unsigned q = st >> 2; q < (st + len4) >> 2; q++)
                qmap[q] = (unsigned char)tid;
        }
        gposs[tid] = p;
    }
    __syncthreads();

    // dense copy-out: thread per uint4 granule, full lane utilization.
    unsigned total4 = lstart[nb] >> 2;     // scan of aligned counts at index nb
    const uint4* st4 = (const uint4*)stage;
    for (unsigned q = tid; q < total4; q += 1024) {
        unsigned b = qmap[q];
        unsigned p = gposs[b];
        unsigned roff = (q << 2) - lstart[b];
        if (p & 0x80000000u) {
            unsigned sp = (p & 0x7FFFFFFFu) + roff;
            #pragma unroll
            for (int t = 0; t < 4; t++) {
                if (sp + t < SPILL_CAP) {
                    unsigned u = stage[(q << 2) + t];
                    spill[sp + t] = make_uint2((b << BSHIFT) | (u & (BSIZE - 1u)),
                                               u & ~(unsigned)(BSIZE - 1));
                }
            }
        } else {
            uint4* dp4 = (uint4*)(bucketbuf + (size_t)b * (unsigned)cap + p + roff);
            *dp4 = st4[q];
        }
    }
}

// grid = nb, 1024 threads. One contiguous uint4-coalesced region per bucket;
// acc[2048] in LDS, two output nodes per thread.
__global__ __launch_bounds__(1024, 2)
void accum_kernel(const unsigned* __restrict__ bucketbuf,
                  const unsigned* __restrict__ gcur,
                  const uint2* __restrict__ spill,
                  const float* __restrict__ v,
                  const float* __restrict__ stim,
                  const float* __restrict__ vrest,
                  const float* __restrict__ tau,
                  float* __restrict__ out,
                  int n_nodes, int nb, int cap) {
    __shared__ float acc[BSIZE];
    int b = blockIdx.x, tid = threadIdx.x;
    acc[tid] = 0.0f;
    acc[tid + 1024] = 0.0f;
    __syncthreads();

    unsigned cnt = gcur[b];
    if (cnt > (unsigned)cap) cnt = (unsigned)cap;
    const unsigned* base = bucketbuf + (size_t)b * (unsigned)cap;
    const uint4* b4 = (const uint4*)base;
    unsigned nq = cnt >> 2;
    for (unsigned i = tid; i < nq; i += 1024) {
        uint4 u = b4[i];
        atomicAdd(&acc[u.x & (BSIZE - 1u)], __uint_as_float(u.x & ~(unsigned)(BSIZE - 1)));
        atomicAdd(&acc[u.y & (BSIZE - 1u)], __uint_as_float(u.y & ~(unsigned)(BSIZE - 1)));
        atomicAdd(&acc[u.z & (BSIZE - 1u)], __uint_as_float(u.z & ~(unsigned)(BSIZE - 1)));
        atomicAdd(&acc[u.w & (BSIZE - 1u)], __uint_as_float(u.w & ~(unsigned)(BSIZE - 1)));
    }
    for (unsigned i = (nq << 2) + tid; i < cnt; i += 1024) {
        unsigned u = base[i];
        atomicAdd(&acc[u & (BSIZE - 1u)], __uint_as_float(u & ~(unsigned)(BSIZE - 1)));
    }

    unsigned sn = gcur[nb];               // spill count: 0 in practice (1 load)
    if (sn) {
        if (sn > SPILL_CAP) sn = SPILL_CAP;
        for (unsigned i = tid; i < sn; i += 1024) {
            uint2 e = spill[i];
            if ((int)(e.x >> BSHIFT) == b)
                atomicAdd(&acc[e.x & (BSIZE - 1u)], __uint_as_float(e.y));
        }
    }
    __syncthreads();

    int i0 = (b << BSHIFT) + tid;
    if (i0 < n_nodes)
        out[i0] = (-v[i0] + acc[tid] + stim[i0] + vrest[i0]) / tau[i0];
    int i1 = i0 + 1024;
    if (i1 < n_nodes)
        out[i1] = (-v[i1] + acc[tid + 1024] + stim[i1] + vrest[i1]) / tau[i1];
}

// ---------------- fallback (agent-scope atomics, always correct) ----------------

__global__ void node_pre_kernel(const float* __restrict__ v,
                                const int* __restrict__ ntype,
                                const float* __restrict__ tp,
                                float* __restrict__ g,
                                float* __restrict__ msg, int n) {
    int i = blockIdx.x * blockDim.x + threadIdx.x;
    if (i < n) {
        float x = v[i];
        x = x > 0.0f ? x : 0.0f;
        g[i] = x * tp[ntype[i]];
        msg[i] = 0.0f;
    }
}

__global__ void edge_scatter_kernel(const int* __restrict__ src,
                                    const int* __restrict__ dst,
                                    const float* __restrict__ w,
                                    const float* __restrict__ g,
                                    float* __restrict__ msg, int n_vec) {
    int i = blockIdx.x * blockDim.x + threadIdx.x;
    if (i < n_vec) {
        int4 s = ((const int4*)src)[i];
        int4 d = ((const int4*)dst)[i];
        float4 wv = ((const float4*)w)[i];
        atomicAdd(&msg[d.x], wv.x * g[s.x]);
        atomicAdd(&msg[d.y], wv.y * g[s.y]);
        atomicAdd(&msg[d.z], wv.z * g[s.z]);
        atomicAdd(&msg[d.w], wv.w * g[s.w]);
    }
}

__global__ void edge_scatter_tail(const int* __restrict__ src,
                                  const int* __restrict__ dst,
                                  const float* __restrict__ w,
                                  const float* __restrict__ g,
                                  float* __restrict__ msg,
                                  int start, int n_edges) {
    int i = start + blockIdx.x * blockDim.x + threadIdx.x;
    if (i < n_edges) atomicAdd(&msg[dst[i]], w[i] * g[src[i]]);
}

__global__ void node_post_kernel(const float* __restrict__ v,
                                 const float* __restrict__ msg,
                                 const float* __restrict__ stim,
                                 const float* __restrict__ vrest,
                                 const float* __restrict__ tau,
                                 float* __restrict__ out, int n) {
    int i = blockIdx.x * blockDim.x + threadIdx.x;
    if (i < n)
        out[i] = (-v[i] + msg[i] + stim[i] + vrest[i]) / tau[i];
}

// ---------------- launch ----------------

extern "C" void kernel_launch(void* const* d_in, const int* in_sizes, int n_in,
                              void* d_out, int out_size, void* d_ws, size_t ws_size,
                              hipStream_t stream) {
    const float* voltage  = (const float*)d_in[0];
    const float* stimulus = (const float*)d_in[1];
    const int*   ntype    = (const int*)d_in[2];
    const int*   edge_idx = (const int*)d_in[3];
    const float* w        = (const float*)d_in[4];
    const float* vrest    = (const float*)d_in[5];
    const float* tau      = (const float*)d_in[6];
    const float* tp       = (const float*)d_in[7];
    float* out = (float*)d_out;

    const int n_nodes = in_sizes[0];
    const int n_edges = in_sizes[4];
    const int* src = edge_idx;
    const int* dst = edge_idx + n_edges;

    const int B = 256;
    const int G = n_edges / 4;
    int nblk = (G + GPB - 1) / GPB;
    if (nblk < 1) nblk = 1;
    const int nb = (n_nodes + BSIZE - 1) / BSIZE;

    auto align256 = [](size_t x) { return (x + 255) & ~(size_t)255; };

    // per-bucket capacity: mean load (65536) + slack. Pad-to-4 adds ~1.5
    // rec/run * nblk(977) ~= 1.5K/bucket; remaining slack covers >8 sigma
    // of binomial spread (sigma ~= 255). Pick the largest slack that fits.
    int base_cap = (int)(((long long)n_edges * BSIZE) / (long long)(n_nodes > 0 ? n_nodes : 1));
    const int slacks[3] = {4096, 3072, 2048};
    int cap = 0;
    size_t g_off = 0, gcur_off = 0, spill_off = 0, bb_off = 0, need = (size_t)-1;
    for (int si = 0; si < 3; si++) {
        int c = (base_cap + slacks[si] + 3) & ~3;
        size_t go  = 0;
        size_t gc  = align256(go + (size_t)n_nodes * 4);
        size_t sp  = align256(gc + (size_t)(nb + 1) * 4);
        size_t bb  = align256(sp + (size_t)SPILL_CAP * 8);
        size_t nd  = align256(bb + (size_t)nb * (size_t)c * 4);
        if (nd <= ws_size) {
            cap = c; g_off = go; gcur_off = gc; spill_off = sp; bb_off = bb; need = nd;
            break;
        }
    }

    if (nb < NBMAX && cap > 0 && need <= ws_size) {
        float*    g         = (float*)((char*)d_ws + g_off);
        unsigned* gcur      = (unsigned*)((char*)d_ws + gcur_off);
        uint2*    spill     = (uint2*)((char*)d_ws + spill_off);
        unsigned* bucketbuf = (unsigned*)((char*)d_ws + bb_off);

        pre_g_kernel<<<(n_nodes + B - 1) / B, B, 0, stream>>>(
            voltage, ntype, tp, g, gcur, n_nodes, nb);
        scatter_kernel<<<nblk, 1024, 0, stream>>>(
            src, dst, w, g, bucketbuf, gcur, spill, G, n_edges, nblk, nb, cap);
        accum_kernel<<<nb, 1024, 0, stream>>>(
            bucketbuf, gcur, spill, voltage, stimulus, vrest, tau, out,
            n_nodes, nb, cap);
    } else {
        float* g   = (float*)d_ws;
        float* msg = (float*)d_ws + n_nodes;
        node_pre_kernel<<<(n_nodes + B - 1) / B, B, 0, stream>>>(
            voltage, ntype, tp, g, msg, n_nodes);
        if (G > 0)
            edge_scatter_kernel<<<(G + B - 1) / B, B, 0, stream>>>(
                src, dst, w, g, msg, G);
        if (G * 4 < n_edges) {
            int rem = n_edges - G * 4;
            edge_scatter_tail<<<(rem + B - 1) / B, B, 0, stream>>>(
                src, dst, w, g, msg, G * 4, n_edges);
        }
        node_post_kernel<<<(n_nodes + B - 1) / B, B, 0, stream>>>(
            voltage, msg, stimulus, vrest, tau, out, n_nodes);
    }
}

// Round 5
// 396.230 us; speedup vs baseline: 1.0901x; 1.0337x over previous
//
#include <hip/hip_runtime.h>

// dv = (-v + segment_sum(w * relu(v[src]) * tp[ntype[src]], dst) + stim + Vrest) / tau
// N_NODES = 500000, N_EDGES = 16000000. edge_index flat: src=[0,E), dst=[E,2E).
//
// R1: agent-scope fp32 atomics -> memory-side RMW wall -> 785us.
// R2: counting sort, direct 4B random writes -> 7x write amp -> 489us scatter.
// R4: LDS-staged bucket sort + coalesced bursts -> 241us scatter @ 19% occ.
// R5: 1024-thr scatter + prefix-derived hist -> 188us scatter.
// R8: private slices + lpref. scatter 144, total 420.8.
// R9: bucket-major global sort (atomic cursor, contiguous accum read).
//     scatter 172, accum -26, total flat 422.7.
// R10: manual MLP hoist WITHIN P1/P2: scatter 182. REGRESSION -- within-phase
//     reorder only perturbs LDS-atomic scheduling. Reverted.
// R11: BSHIFT 11 (2048 buckets, nb=245): scatter 161, total 411.5.
// R12: dense copy-out (4-aligned LDS runs, q->bucket byte map, b128+dwordx4):
//     scatter 156.5, VALUBusy 12.5->6.3. total 409.6. P1/P2 core is the
//     stubborn ~130-155us: 4.8 cyc/edge vs ~2 accounted; g-gather ~1
//     cyc/edge is the largest item and sits serialized inside P2.
// R13 (this): CROSS-PHASE gather prefetch. Issue all 16 g[src] gathers in
//     pass 1 (before hist atomics), hold in regs across the scan barrier;
//     scan's LDS/shfl work absorbs the gather latency; P2 becomes pure
//     stream+LDS. Unlike R10 this moves latency across phases, which the
//     compiler cannot (loads don't cross __syncthreads). VGPR ~48-56,
//     still 8 waves/EU. Predict scatter ~130us, conflicts +~1M (accepted).

#define BSHIFT 11
#define BSIZE  2048              // nodes per bucket
#define NBMAX  256               // > nb = ceil(500000/2048) = 245; fits uint8 map
#define GPB    4096              // int4 groups per scatter block = 16384 edges
#define EPB    (GPB * 4)
#define EPBP   (EPB + 1024)      // stage + per-bucket 4-alignment padding (<=735)
#define MAPSZ  (EPBP / 4)        // uint4-granule -> bucket byte map
#define SPILL_CAP 131072

// pack: round-to-nearest on the stolen low bits, then steal 11 for local dst
__device__ __forceinline__ unsigned pack_rec(float x, int d) {
    return ((__float_as_uint(x) + (unsigned)(BSIZE >> 1)) & ~(unsigned)(BSIZE - 1)) |
           ((unsigned)d & (BSIZE - 1));
}

// ---------------- main path ----------------

__global__ void pre_g_kernel(const float* __restrict__ v,
                             const int* __restrict__ ntype,
                             const float* __restrict__ tp,
                             float* __restrict__ g,
                             unsigned* __restrict__ gcur,
                             int n, int nb) {
    int i = blockIdx.x * blockDim.x + threadIdx.x;
    if (i < n) {
        float x = v[i];
        x = x > 0.0f ? x : 0.0f;
        g[i] = x * tp[ntype[i]];
    }
    if (i <= nb) gcur[i] = 0u;   // gcur[0..nb-1] = bucket cursors, gcur[nb] = spill count
}

// grid = nblk, 1024 threads. Bins one 16K-edge chunk into 4-record-aligned
// per-bucket runs in LDS, reserves global per-bucket space via atomic
// cursor, then copies out densely (thread-per-uint4, byte map).
__global__ __launch_bounds__(1024, 8)
void scatter_kernel(const int* __restrict__ src,
                    const int* __restrict__ dst,
                    const float* __restrict__ w,
                    const float* __restrict__ g,
                    unsigned* __restrict__ bucketbuf,
                    unsigned* __restrict__ gcur,
                    uint2* __restrict__ spill,
                    int G, int n_edges, int nblk, int nb, int cap) {
    __shared__ unsigned stage[EPBP];       // 69.6 KB
    __shared__ unsigned lstart[NBMAX];     // 4-aligned exclusive starts (1 KB)
    __shared__ unsigned lcur[NBMAX];       // working cursors            (1 KB)
    __shared__ unsigned gposs[NBMAX];      // global positions           (1 KB)
    __shared__ unsigned char qmap[MAPSZ];  // uint4-granule -> bucket    (4.3 KB)
    __shared__ unsigned wsum[16];
    int blk = blockIdx.x, tid = threadIdx.x;
    int wid = tid >> 6, lane = tid & 63;
    bool last = (blk == nblk - 1);

    if (tid < NBMAX) lcur[tid] = 0;
    __syncthreads();

    const int4*   s4 = (const int4*)src;
    const int4*   d4 = (const int4*)dst;
    const float4* w4 = (const float4*)w;
    int gstart = blk * GPB;
    int gend = gstart + GPB; if (gend > G) gend = G;
    bool full = (gend - gstart) == GPB;

    // pass 1: dst loads + g-gather ISSUE (prefetch held across the scan),
    // then local histogram. The gather latency drains during the scan phase.
    int4 dreg[4];
    float gv[16];
    if (full) {
        int i0 = gstart + tid;
        int4 dA = d4[i0], dB = d4[i0 + 1024], dC = d4[i0 + 2048], dD = d4[i0 + 3072];
        int4 sA = s4[i0], sB = s4[i0 + 1024], sC = s4[i0 + 2048], sD = s4[i0 + 3072];
        gv[0]  = g[sA.x]; gv[1]  = g[sA.y]; gv[2]  = g[sA.z]; gv[3]  = g[sA.w];
        gv[4]  = g[sB.x]; gv[5]  = g[sB.y]; gv[6]  = g[sB.z]; gv[7]  = g[sB.w];
        gv[8]  = g[sC.x]; gv[9]  = g[sC.y]; gv[10] = g[sC.z]; gv[11] = g[sC.w];
        gv[12] = g[sD.x]; gv[13] = g[sD.y]; gv[14] = g[sD.z]; gv[15] = g[sD.w];
        dreg[0] = dA; dreg[1] = dB; dreg[2] = dC; dreg[3] = dD;
        atomicAdd(&lcur[((unsigned)dA.x) >> BSHIFT], 1u);
        atomicAdd(&lcur[((unsigned)dA.y) >> BSHIFT], 1u);
        atomicAdd(&lcur[((unsigned)dA.z) >> BSHIFT], 1u);
        atomicAdd(&lcur[((unsigned)dA.w) >> BSHIFT], 1u);
        atomicAdd(&lcur[((unsigned)dB.x) >> BSHIFT], 1u);
        atomicAdd(&lcur[((unsigned)dB.y) >> BSHIFT], 1u);
        atomicAdd(&lcur[((unsigned)dB.z) >> BSHIFT], 1u);
        atomicAdd(&lcur[((unsigned)dB.w) >> BSHIFT], 1u);
        atomicAdd(&lcur[((unsigned)dC.x) >> BSHIFT], 1u);
        atomicAdd(&lcur[((unsigned)dC.y) >> BSHIFT], 1u);
        atomicAdd(&lcur[((unsigned)dC.z) >> BSHIFT], 1u);
        atomicAdd(&lcur[((unsigned)dC.w) >> BSHIFT], 1u);
        atomicAdd(&lcur[((unsigned)dD.x) >> BSHIFT], 1u);
        atomicAdd(&lcur[((unsigned)dD.y) >> BSHIFT], 1u);
        atomicAdd(&lcur[((unsigned)dD.z) >> BSHIFT], 1u);
        atomicAdd(&lcur[((unsigned)dD.w) >> BSHIFT], 1u);
    } else {
        #pragma unroll
        for (int k = 0; k < 4; k++) {
            int i = gstart + tid + k * 1024;
            if (i < gend) {
                int4 d = d4[i];
                dreg[k] = d;
                atomicAdd(&lcur[((unsigned)d.x) >> BSHIFT], 1u);
                atomicAdd(&lcur[((unsigned)d.y) >> BSHIFT], 1u);
                atomicAdd(&lcur[((unsigned)d.z) >> BSHIFT], 1u);
                atomicAdd(&lcur[((unsigned)d.w) >> BSHIFT], 1u);
            }
        }
    }
    if (last) {
        for (int i = G * 4 + tid; i < n_edges; i += 1024)
            atomicAdd(&lcur[((unsigned)dst[i]) >> BSHIFT], 1u);
    }
    __syncthreads();

    // exclusive scan over NBMAX=256 entries of the 4-ALIGNED counts, so
    // every bucket's stage region starts on a uint4 boundary. (This phase
    // also hides the gv[] gather latency issued above.)
    unsigned rawc = (tid < NBMAX) ? lcur[tid] : 0u;
    unsigned cntv = (rawc + 3u) & ~3u;
    unsigned inc = cntv;
    #pragma unroll
    for (int o = 1; o < 64; o <<= 1) {
        unsigned t = __shfl_up(inc, o, 64);
        if (lane >= o) inc += t;
    }
    if (lane == 63) wsum[wid] = inc;
    __syncthreads();
    if (tid < 64) {
        unsigned x = (lane < 16) ? wsum[lane] : 0u;
        unsigned xi = x;
        #pragma unroll
        for (int o = 1; o < 16; o <<= 1) {
            unsigned t = __shfl_up(xi, o, 64);
            if (lane >= o) xi += t;
        }
        if (lane < 16) wsum[lane] = xi - x;   // exclusive wave offsets
    }
    __syncthreads();
    if (tid < NBMAX) {
        unsigned excl = inc - cntv + wsum[wid];
        lstart[tid] = excl;       // 4-aligned
        lcur[tid] = excl;
    }
    __syncthreads();

    // pass 2: bin packed records. Full path: pure stream + LDS (g values
    // already in registers).
    if (full) {
        int i0 = gstart + tid;
        #pragma unroll
        for (int k = 0; k < 4; k++) {
            float4 wv = w4[i0 + k * 1024];
            int4 d = dreg[k];
            unsigned pos;
            pos = atomicAdd(&lcur[((unsigned)d.x) >> BSHIFT], 1u);
            stage[pos] = pack_rec(wv.x * gv[4 * k + 0], d.x);
            pos = atomicAdd(&lcur[((unsigned)d.y) >> BSHIFT], 1u);
            stage[pos] = pack_rec(wv.y * gv[4 * k + 1], d.y);
            pos = atomicAdd(&lcur[((unsigned)d.z) >> BSHIFT], 1u);
            stage[pos] = pack_rec(wv.z * gv[4 * k + 2], d.z);
            pos = atomicAdd(&lcur[((unsigned)d.w) >> BSHIFT], 1u);
            stage[pos] = pack_rec(wv.w * gv[4 * k + 3], d.w);
        }
    } else {
        #pragma unroll
        for (int k = 0; k < 4; k++) {
            int i = gstart + tid + k * 1024;
            if (i < gend) {
                int4 s = s4[i]; float4 wv = w4[i]; int4 d = dreg[k];
                unsigned pos;
                pos = atomicAdd(&lcur[((unsigned)d.x) >> BSHIFT], 1u);
                stage[pos] = pack_rec(wv.x * g[s.x], d.x);
                pos = atomicAdd(&lcur[((unsigned)d.y) >> BSHIFT], 1u);
                stage[pos] = pack_rec(wv.y * g[s.y], d.y);
                pos = atomicAdd(&lcur[((unsigned)d.z) >> BSHIFT], 1u);
                stage[pos] = pack_rec(wv.z * g[s.z], d.z);
                pos = atomicAdd(&lcur[((unsigned)d.w) >> BSHIFT], 1u);
                stage[pos] = pack_rec(wv.w * g[s.w], d.w);
            }
        }
    }
    if (last) {
        for (int i = G * 4 + tid; i < n_edges; i += 1024) {
            int dd = dst[i];
            unsigned b = ((unsigned)dd) >> BSHIFT;
            unsigned pos = atomicAdd(&lcur[b], 1u);
            stage[pos] = pack_rec(w[i] * g[src[i]], dd);
        }
    }
    __syncthreads();

    // reserve + pad + map phase (one thread per bucket)
    if (tid < nb) {
        unsigned st   = lstart[tid];
        unsigned end  = lcur[tid];
        unsigned len  = end - st;
        unsigned len4 = (len + 3u) & ~3u;
        unsigned p = 0u;
        if (len) {
            p = atomicAdd(&gcur[tid], len4);
            if (p + len4 > (unsigned)cap) {          // many-sigma event: spill run
                atomicSub(&gcur[tid], len4);
                unsigned sp = atomicAdd(&gcur[nb], len4);
                p = 0x80000000u | sp;
            }
            for (unsigned j = end; j < st + len4; j++)
                stage[j] = j & (unsigned)(BSIZE - 1);   // value +0.0, spread idx
            for (unsigned q = st >> 2; q < (st + len4) >> 2; q++)
                qmap[q] = (unsigned char)tid;
        }
        gposs[tid] = p;
    }
    __syncthreads();

    // dense copy-out: thread per uint4 granule, full lane utilization.
    unsigned total4 = lstart[nb] >> 2;     // scan of aligned counts at index nb
    const uint4* st4 = (const uint4*)stage;
    for (unsigned q = tid; q < total4; q += 1024) {
        unsigned b = qmap[q];
        unsigned p = gposs[b];
        unsigned roff = (q << 2) - lstart[b];
        if (p & 0x80000000u) {
            unsigned sp = (p & 0x7FFFFFFFu) + roff;
            #pragma unroll
            for (int t = 0; t < 4; t++) {
                if (sp + t < SPILL_CAP) {
                    unsigned u = stage[(q << 2) + t];
                    spill[sp + t] = make_uint2((b << BSHIFT) | (u & (BSIZE - 1u)),
                                               u & ~(unsigned)(BSIZE - 1));
                }
            }
        } else {
            uint4* dp4 = (uint4*)(bucketbuf + (size_t)b * (unsigned)cap + p + roff);
            *dp4 = st4[q];
        }
    }
}

// grid = nb, 1024 threads. One contiguous uint4-coalesced region per bucket;
// acc[2048] in LDS, two output nodes per thread.
__global__ __launch_bounds__(1024, 2)
void accum_kernel(const unsigned* __restrict__ bucketbuf,
                  const unsigned* __restrict__ gcur,
                  const uint2* __restrict__ spill,
                  const float* __restrict__ v,
                  const float* __restrict__ stim,
                  const float* __restrict__ vrest,
                  const float* __restrict__ tau,
                  float* __restrict__ out,
                  int n_nodes, int nb, int cap) {
    __shared__ float acc[BSIZE];
    int b = blockIdx.x, tid = threadIdx.x;
    acc[tid] = 0.0f;
    acc[tid + 1024] = 0.0f;
    __syncthreads();

    unsigned cnt = gcur[b];
    if (cnt > (unsigned)cap) cnt = (unsigned)cap;
    const unsigned* base = bucketbuf + (size_t)b * (unsigned)cap;
    const uint4* b4 = (const uint4*)base;
    unsigned nq = cnt >> 2;
    for (unsigned i = tid; i < nq; i += 1024) {
        uint4 u = b4[i];
        atomicAdd(&acc[u.x & (BSIZE - 1u)], __uint_as_float(u.x & ~(unsigned)(BSIZE - 1)));
        atomicAdd(&acc[u.y & (BSIZE - 1u)], __uint_as_float(u.y & ~(unsigned)(BSIZE - 1)));
        atomicAdd(&acc[u.z & (BSIZE - 1u)], __uint_as_float(u.z & ~(unsigned)(BSIZE - 1)));
        atomicAdd(&acc[u.w & (BSIZE - 1u)], __uint_as_float(u.w & ~(unsigned)(BSIZE - 1)));
    }
    for (unsigned i = (nq << 2) + tid; i < cnt; i += 1024) {
        unsigned u = base[i];
        atomicAdd(&acc[u & (BSIZE - 1u)], __uint_as_float(u & ~(unsigned)(BSIZE - 1)));
    }

    unsigned sn = gcur[nb];               // spill count: 0 in practice (1 load)
    if (sn) {
        if (sn > SPILL_CAP) sn = SPILL_CAP;
        for (unsigned i = tid; i < sn; i += 1024) {
            uint2 e = spill[i];
            if ((int)(e.x >> BSHIFT) == b)
                atomicAdd(&acc[e.x & (BSIZE - 1u)], __uint_as_float(e.y));
        }
    }
    __syncthreads();

    int i0 = (b << BSHIFT) + tid;
    if (i0 < n_nodes)
        out[i0] = (-v[i0] + acc[tid] + stim[i0] + vrest[i0]) / tau[i0];
    int i1 = i0 + 1024;
    if (i1 < n_nodes)
        out[i1] = (-v[i1] + acc[tid + 1024] + stim[i1] + vrest[i1]) / tau[i1];
}

// ---------------- fallback (agent-scope atomics, always correct) ----------------

__global__ void node_pre_kernel(const float* __restrict__ v,
                                const int* __restrict__ ntype,
                                const float* __restrict__ tp,
                                float* __restrict__ g,
                                float* __restrict__ msg, int n) {
    int i = blockIdx.x * blockDim.x + threadIdx.x;
    if (i < n) {
        float x = v[i];
        x = x > 0.0f ? x : 0.0f;
        g[i] = x * tp[ntype[i]];
        msg[i] = 0.0f;
    }
}

__global__ void edge_scatter_kernel(const int* __restrict__ src,
                                    const int* __restrict__ dst,
                                    const float* __restrict__ w,
                                    const float* __restrict__ g,
                                    float* __restrict__ msg, int n_vec) {
    int i = blockIdx.x * blockDim.x + threadIdx.x;
    if (i < n_vec) {
        int4 s = ((const int4*)src)[i];
        int4 d = ((const int4*)dst)[i];
        float4 wv = ((const float4*)w)[i];
        atomicAdd(&msg[d.x], wv.x * g[s.x]);
        atomicAdd(&msg[d.y], wv.y * g[s.y]);
        atomicAdd(&msg[d.z], wv.z * g[s.z]);
        atomicAdd(&msg[d.w], wv.w * g[s.w]);
    }
}

__global__ void edge_scatter_tail(const int* __restrict__ src,
                                  const int* __restrict__ dst,
                                  const float* __restrict__ w,
                                  const float* __restrict__ g,
                                  float* __restrict__ msg,
                                  int start, int n_edges) {
    int i = start + blockIdx.x * blockDim.x + threadIdx.x;
    if (i < n_edges) atomicAdd(&msg[dst[i]], w[i] * g[src[i]]);
}

__global__ void node_post_kernel(const float* __restrict__ v,
                                 const float* __restrict__ msg,
                                 const float* __restrict__ stim,
                                 const float* __restrict__ vrest,
                                 const float* __restrict__ tau,
                                 float* __restrict__ out, int n) {
    int i = blockIdx.x * blockDim.x + threadIdx.x;
    if (i < n)
        out[i] = (-v[i] + msg[i] + stim[i] + vrest[i]) / tau[i];
}

// ---------------- launch ----------------

extern "C" void kernel_launch(void* const* d_in, const int* in_sizes, int n_in,
                              void* d_out, int out_size, void* d_ws, size_t ws_size,
                              hipStream_t stream) {
    const float* voltage  = (const float*)d_in[0];
    const float* stimulus = (const float*)d_in[1];
    const int*   ntype    = (const int*)d_in[2];
    const int*   edge_idx = (const int*)d_in[3];
    const float* w        = (const float*)d_in[4];
    const float* vrest    = (const float*)d_in[5];
    const float* tau      = (const float*)d_in[6];
    const float* tp       = (const float*)d_in[7];
    float* out = (float*)d_out;

    const int n_nodes = in_sizes[0];
    const int n_edges = in_sizes[4];
    const int* src = edge_idx;
    const int* dst = edge_idx + n_edges;

    const int B = 256;
    const int G = n_edges / 4;
    int nblk = (G + GPB - 1) / GPB;
    if (nblk < 1) nblk = 1;
    const int nb = (n_nodes + BSIZE - 1) / BSIZE;

    auto align256 = [](size_t x) { return (x + 255) & ~(size_t)255; };

    // per-bucket capacity: mean load (65536) + slack. Pad-to-4 adds ~1.5
    // rec/run * nblk(977) ~= 1.5K/bucket; remaining slack covers >8 sigma
    // of binomial spread (sigma ~= 255). Pick the largest slack that fits.
    int base_cap = (int)(((long long)n_edges * BSIZE) / (long long)(n_nodes > 0 ? n_nodes : 1));
    const int slacks[3] = {4096, 3072, 2048};
    int cap = 0;
    size_t g_off = 0, gcur_off = 0, spill_off = 0, bb_off = 0, need = (size_t)-1;
    for (int si = 0; si < 3; si++) {
        int c = (base_cap + slacks[si] + 3) & ~3;
        size_t go  = 0;
        size_t gc  = align256(go + (size_t)n_nodes * 4);
        size_t sp  = align256(gc + (size_t)(nb + 1) * 4);
        size_t bb  = align256(sp + (size_t)SPILL_CAP * 8);
        size_t nd  = align256(bb + (size_t)nb * (size_t)c * 4);
        if (nd <= ws_size) {
            cap = c; g_off = go; gcur_off = gc; spill_off = sp; bb_off = bb; need = nd;
            break;
        }
    }

    if (nb < NBMAX && cap > 0 && need <= ws_size) {
        float*    g         = (float*)((char*)d_ws + g_off);
        unsigned* gcur      = (unsigned*)((char*)d_ws + gcur_off);
        uint2*    spill     = (uint2*)((char*)d_ws + spill_off);
        unsigned* bucketbuf = (unsigned*)((char*)d_ws + bb_off);

        pre_g_kernel<<<(n_nodes + B - 1) / B, B, 0, stream>>>(
            voltage, ntype, tp, g, gcur, n_nodes, nb);
        scatter_kernel<<<nblk, 1024, 0, stream>>>(
            src, dst, w, g, bucketbuf, gcur, spill, G, n_edges, nblk, nb, cap);
        accum_kernel<<<nb, 1024, 0, stream>>>(
            bucketbuf, gcur, spill, voltage, stimulus, vrest, tau, out,
            n_nodes, nb, cap);
    } else {
        float* g   = (float*)d_ws;
        float* msg = (float*)d_ws + n_nodes;
        node_pre_kernel<<<(n_nodes + B - 1) / B, B, 0, stream>>>(
            voltage, ntype, tp, g, msg, n_nodes);
        if (G > 0)
            edge_scatter_kernel<<<(G + B - 1) / B, B, 0, stream>>>(
                src, dst, w, g, msg, G);
        if (G * 4 < n_edges) {
            int rem = n_edges - G * 4;
            edge_scatter_tail<<<(rem + B - 1) / B, B, 0, stream>>>(
                src, dst, w, g, msg, G * 4, n_edges);
        }
        node_post_kernel<<<(n_nodes + B - 1) / B, B, 0, stream>>>(
            voltage, msg, stimulus, vrest, tau, out, n_nodes);
    }
}